// Round 6
// baseline (284.199 us; speedup 1.0000x reference)
//
#include <hip/hip_runtime.h>

// ImportanceAggregator, fully fused:
//   K0 convert_all : feat fp32 -> featb bf16  AND  W -> wtp bf16 (MFMA B-frag order)
//   K1 fused       : one wave per 16 nodes, barrier-light, 3 phases:
//                    P1 pool 16 rows -> private LDS tile (16 gathers in flight)
//                    P2 128x MFMA 16x16x32 vs packed-B wtp (R3-proven core)
//                    P3 LN + per-wave LDS transpose -> coalesced float4 stores
// Rationale: pool is at its compulsory L2-fill floor (~175 MB @ ~3.2 TB/s, R2-R5);
// fusing lets the former 49-63 us gemm_ln hide inside the fetch-bound phase via
// 12 independent waves/CU, and kills the 50 MB agg HBM roundtrip.
// R4 lesson honored: idx[]/w[] arrays only with fully-unrolled constant indices.

#define NN   50000
#define KNB  16
#define D    256
#define RPB  16          // rows (nodes) per block == per wave
#define ASTR 264         // agg LDS row stride in shorts (512 B + 16 B pad)

typedef __attribute__((ext_vector_type(8))) short short8;   // 8 x bf16 (4 VGPRs)
typedef __attribute__((ext_vector_type(4))) float f32x4;

static __device__ __forceinline__ unsigned short f2bf(float x) {
    unsigned int u = __float_as_uint(x);
    return (unsigned short)((u + 0x7FFFu + ((u >> 16) & 1u)) >> 16);  // RNE
}
static __device__ __forceinline__ float bf2f(unsigned short h) {
    return __uint_as_float((unsigned int)h << 16);
}

// ---------------- K0: both conversions in one dispatch --------------------
// blocks [0,6250): feat fp32 -> bf16 (8 elem/thread).
// blocks [6250,6282): W -> bf16 packed so frag g=(c*8+kb)*64+lane holds
//   B[k = (lane>>4)*8 + kb*32 + j][n = c*16 + (lane&15)]  (R3-proven layout).
__global__ __launch_bounds__(256) void convert_all(const float* __restrict__ feat,
                                                   const float* __restrict__ Wm,
                                                   unsigned short* __restrict__ featb,
                                                   unsigned short* __restrict__ wtp) {
    if (blockIdx.x < 6250) {
        const size_t g = (size_t)blockIdx.x * 256 + threadIdx.x;
        const float4 a = *(const float4*)(feat + g * 8);
        const float4 b = *(const float4*)(feat + g * 8 + 4);
        short8 o;
        o[0] = (short)f2bf(a.x); o[1] = (short)f2bf(a.y);
        o[2] = (short)f2bf(a.z); o[3] = (short)f2bf(a.w);
        o[4] = (short)f2bf(b.x); o[5] = (short)f2bf(b.y);
        o[6] = (short)f2bf(b.z); o[7] = (short)f2bf(b.w);
        *(short8*)(featb + g * 8) = o;
    } else {
        const int g    = (blockIdx.x - 6250) * 256 + threadIdx.x;   // 0..8191
        const int lane = g & 63;
        const int kb   = (g >> 6) & 7;
        const int c    = g >> 9;
        const int n    = c * 16 + (lane & 15);
        const int k0   = kb * 32 + (lane >> 4) * 8;
        short8 v;
        #pragma unroll
        for (int j = 0; j < 8; ++j) v[j] = (short)f2bf(Wm[(size_t)(k0 + j) * D + n]);
        *(short8*)(wtp + (size_t)g * 8) = v;
    }
}

// ---------------- K1: fused pool + MFMA GEMM + LayerNorm ------------------
__global__ __launch_bounds__(64, 3) void fused(const unsigned short* __restrict__ featb,
                                               const int*   __restrict__ nbr,
                                               const float* __restrict__ iw,
                                               const unsigned short* __restrict__ wtp,
                                               const float* __restrict__ bias,
                                               const float* __restrict__ gamma,
                                               const float* __restrict__ beta,
                                               float* __restrict__ out) {
    __shared__ unsigned short sAgg[RPB * ASTR];        // 8448 B, wave-private

    const int  lane    = threadIdx.x;                  // 0..63
    const int  quad    = lane >> 4;
    const int  l15     = lane & 15;
    const long rowbase = (long)blockIdx.x * RPB;       // exact: 3125*16 = 50000

    // ---- Phase 1: pool 16 nodes into sAgg (bf16, fp32 accumulate) --------
    #pragma unroll 1
    for (int i = 0; i < RPB; ++i) {
        const long n = rowbase + i;                    // wave-uniform -> scalar loads
        int   idx[KNB];
        float w[KNB];
        #pragma unroll
        for (int k = 0; k < KNB; ++k) {                // constant-indexed -> registers
            idx[k] = nbr[n * KNB + k];
            w[k]   = iw [n * KNB + k];
        }
        float ws = 0.f;
        #pragma unroll
        for (int k = 0; k < KNB; ++k) ws += w[k];
        const bool  zs  = (ws == 0.f);
        const float inv = zs ? (1.f / KNB) : (1.f / ws);

        float4 p = make_float4(0.f, 0.f, 0.f, 0.f);
        #pragma unroll
        for (int k = 0; k < KNB; ++k) {                // 16 gathers in flight
            const float   wk = zs ? inv : (w[k] * inv);
            const ushort4 u  = *(const ushort4*)(featb + (size_t)idx[k] * D + lane * 4);
            p.x += wk * bf2f(u.x); p.y += wk * bf2f(u.y);
            p.z += wk * bf2f(u.z); p.w += wk * bf2f(u.w);
        }
        ushort4 o;
        o.x = f2bf(p.x); o.y = f2bf(p.y); o.z = f2bf(p.z); o.w = f2bf(p.w);
        *(ushort4*)(sAgg + i * ASTR + lane * 4) = o;   // 2-way bank alias = free
    }
    __syncthreads();                                   // 1 wave: just a waitcnt

    // ---- Phase 2: 16x256 @ 256x256 via 128 MFMAs (R3-proven core) --------
    const unsigned short* ap = sAgg + (size_t)l15 * ASTR + quad * 8;
    const short8* wv = (const short8*)wtp;

    f32x4 acc[16];
    #pragma unroll
    for (int c = 0; c < 16; ++c) acc[c] = (f32x4){0.f, 0.f, 0.f, 0.f};

    #pragma unroll
    for (int kb = 0; kb < 8; ++kb) {
        const short8 a = *(const short8*)(ap + kb * 32);   // ds_read_b128, ~2-way
        #pragma unroll
        for (int c = 0; c < 16; ++c) {
            const short8 b = wv[(size_t)(c * 8 + kb) * 64 + lane];  // dense 1 KB, L2-hot
            acc[c] = __builtin_amdgcn_mfma_f32_16x16x32_bf16(a, b, acc[c], 0, 0, 0);
        }
    }

    // ---- Phase 3: +bias, LN, transpose via reused LDS, float4 stores -----
    float bv[16], gv[16], btv[16];
    #pragma unroll
    for (int c = 0; c < 16; ++c) {
        bv[c]  = bias [c * 16 + l15];
        gv[c]  = gamma[c * 16 + l15];
        btv[c] = beta [c * 16 + l15];
    }
    float* fsh = (float*)sAgg;                         // 2112 floats available
    #pragma unroll
    for (int j = 0; j < 4; ++j) {      // C/D: row = quad*4 + j, col = c*16 + l15
        float s = 0.f, sq = 0.f;
        #pragma unroll
        for (int c = 0; c < 16; ++c) {
            const float v = acc[c][j] + bv[c];
            s += v; sq += v * v;
        }
        #pragma unroll
        for (int off = 1; off < 16; off <<= 1) {       // reduce across l15 (same quad)
            s  += __shfl_xor(s,  off, 64);
            sq += __shfl_xor(sq, off, 64);
        }
        const float mean = s * (1.f / D);
        const float var  = sq * (1.f / D) - mean * mean;   // biased (torch LN)
        const float rstd = rsqrtf(var + 1e-5f);
        #pragma unroll
        for (int c = 0; c < 16; ++c)                   // stride 265: <=2-way conflicts
            fsh[quad * 265 + c * 16 + l15] =
                (acc[c][j] + bv[c] - mean) * rstd * gv[c] + btv[c];
        __syncthreads();                               // writes visible (waitcnt)
        #pragma unroll
        for (int p = 0; p < 4; ++p) {                  // rows {j,4+j,8+j,12+j}
            const long r = rowbase + p * 4 + j;
            const float4 vv = *(const float4*)(fsh + p * 265 + lane * 4);
            *(float4*)(out + r * D + lane * 4) = vv;   // coalesced 1 KB/instr
        }
        __syncthreads();                               // reads done before next j
    }
}

extern "C" void kernel_launch(void* const* d_in, const int* in_sizes, int n_in,
                              void* d_out, int out_size, void* d_ws, size_t ws_size,
                              hipStream_t stream) {
    const float* feat = (const float*)d_in[0];
    const int*   nbr  = (const int*)d_in[1];
    const float* iw   = (const float*)d_in[2];
    const float* Wm   = (const float*)d_in[3];
    const float* b    = (const float*)d_in[4];
    const float* g    = (const float*)d_in[5];
    const float* be   = (const float*)d_in[6];
    float*       out  = (float*)d_out;

    unsigned short* wtp   = (unsigned short*)d_ws;                   // 128 KB
    unsigned short* featb = (unsigned short*)((char*)d_ws + 131072); // 25.6 MB

    convert_all<<<dim3(6250 + 32), dim3(256), 0, stream>>>(feat, Wm, featb, wtp);
    fused      <<<dim3(NN / RPB),  dim3(64),  0, stream>>>(featb, nbr, iw, wtp,
                                                           b, g, be, out);
}

// Round 7
// 221.340 us; speedup vs baseline: 1.2840x; 1.2840x over previous
//
#include <hip/hip_runtime.h>

// ImportanceAggregator pipeline (best-known structure = R3, gemm_ln rebuilt):
//   K0 convert_all : feat fp32 -> featb bf16  AND  W -> wtp bf16 (B-frag order)
//   K1 pool_b      : agg[n] = sum_k w~[n,k] * featb[nbr[n,k]]; one wave/node.
//                    At the L3->L2 fill floor (~175 MB @ ~3.1 TB/s, R2-R6).
//   K2 gemm_ln     : out = LN(agg @ W + b)*gamma + beta via MFMA 16x16x32.
//                    R3 core + per-WAVE 4x272f LDS transpose (17.4 KB/block,
//                    no barriers) + (256,4) -> 16 waves/CU + float4 stores.
// Lessons pinned: no 64-thread blocks (R6: 8 wg/CU slot limit, 24% occ);
// no hoisted runtime-indexed arrays (R4: alloca->LDS, 3.6M bank conflicts);
// coalesced float4 epilogue beats direct segment stores (R3 vs R5).
// agg bf16 rows live in d_out at 1 KB stride; each gemm_ln block reads only its
// own 64 rows then overwrites exactly those rows -> no cross-block hazard.

#define NN   50000
#define KNB  16
#define D    256

typedef __attribute__((ext_vector_type(8))) short short8;   // 8 x bf16 (4 VGPRs)
typedef __attribute__((ext_vector_type(4))) float f32x4;

static __device__ __forceinline__ unsigned short f2bf(float x) {
    unsigned int u = __float_as_uint(x);
    return (unsigned short)((u + 0x7FFFu + ((u >> 16) & 1u)) >> 16);  // RNE
}
static __device__ __forceinline__ float bf2f(unsigned short h) {
    return __uint_as_float((unsigned int)h << 16);
}

// ---------------- K0: both conversions in one dispatch --------------------
// blocks [0,6250): feat fp32 -> bf16 (8 elem/thread).
// blocks [6250,6282): W -> bf16 packed so frag g=(c*8+kb)*64+lane holds
//   B[k = (lane>>4)*8 + kb*32 + j][n = c*16 + (lane&15)]  (R3-proven layout).
__global__ __launch_bounds__(256) void convert_all(const float* __restrict__ feat,
                                                   const float* __restrict__ Wm,
                                                   unsigned short* __restrict__ featb,
                                                   unsigned short* __restrict__ wtp) {
    if (blockIdx.x < 6250) {
        const size_t g = (size_t)blockIdx.x * 256 + threadIdx.x;
        const float4 a = *(const float4*)(feat + g * 8);
        const float4 b = *(const float4*)(feat + g * 8 + 4);
        short8 o;
        o[0] = (short)f2bf(a.x); o[1] = (short)f2bf(a.y);
        o[2] = (short)f2bf(a.z); o[3] = (short)f2bf(a.w);
        o[4] = (short)f2bf(b.x); o[5] = (short)f2bf(b.y);
        o[6] = (short)f2bf(b.z); o[7] = (short)f2bf(b.w);
        *(short8*)(featb + g * 8) = o;
    } else {
        const int g    = (blockIdx.x - 6250) * 256 + threadIdx.x;   // 0..8191
        const int lane = g & 63;
        const int kb   = (g >> 6) & 7;
        const int c    = g >> 9;
        const int n    = c * 16 + (lane & 15);
        const int k0   = kb * 32 + (lane >> 4) * 8;
        short8 v;
        #pragma unroll
        for (int j = 0; j < 8; ++j) v[j] = (short)f2bf(Wm[(size_t)(k0 + j) * D + n]);
        *(short8*)(wtp + (size_t)g * 8) = v;
    }
}

// ---------------- K1: weighted neighbor pooling (bf16 gathers) ------------
// R3-proven form. NOTE: idx[]/w[] must stay inside the loop with constant
// indices only -> registers (hoisting triggers LDS promotion, see R4).
__global__ __launch_bounds__(256, 8) void pool_b(const unsigned short* __restrict__ featb,
                                                 const int*   __restrict__ nbr,
                                                 const float* __restrict__ iw,
                                                 unsigned short* __restrict__ aggb) {
    const int  t    = threadIdx.x;
    const int  lane = t & 63;
    const int  wq   = t >> 6;
    const long n    = (long)blockIdx.x * 4 + wq;   // one wave per node

    float ws = 0.f;
    #pragma unroll
    for (int k = 0; k < KNB; ++k) ws += iw[n * KNB + k];
    const bool  zs  = (ws == 0.f);
    const float inv = zs ? (1.f / KNB) : (1.f / ws);

    float4 p = make_float4(0.f, 0.f, 0.f, 0.f);
    #pragma unroll 1
    for (int kb = 0; kb < KNB; kb += 8) {          // 8 gathers in flight per batch
        int   idx[8];
        float w[8];
        #pragma unroll
        for (int k = 0; k < 8; ++k) {
            idx[k] = nbr[n * KNB + kb + k];
            w[k]   = iw [n * KNB + kb + k];
        }
        #pragma unroll
        for (int k = 0; k < 8; ++k) {
            const float   wk = zs ? inv : (w[k] * inv);
            const ushort4 u  = *(const ushort4*)(featb + (size_t)idx[k] * D + lane * 4);
            p.x += wk * bf2f(u.x); p.y += wk * bf2f(u.y);
            p.z += wk * bf2f(u.z); p.w += wk * bf2f(u.w);
        }
    }
    ushort4 o;
    o.x = f2bf(p.x); o.y = f2bf(p.y); o.z = f2bf(p.z); o.w = f2bf(p.w);
    *(ushort4*)(aggb + (size_t)n * 512 + lane * 4) = o;   // row n @ 1 KB stride
}

// Fallback (ws too small for featb): fp32 gathers, one node per wave.
__global__ __launch_bounds__(256, 8) void pool_f(const float* __restrict__ feat,
                                                 const int*   __restrict__ nbr,
                                                 const float* __restrict__ iw,
                                                 unsigned short* __restrict__ aggb) {
    const int  t    = threadIdx.x;
    const int  lane = t & 63;
    const int  wq   = t >> 6;
    const long n    = (long)blockIdx.x * 4 + wq;
    float ws = 0.f;
    #pragma unroll
    for (int k = 0; k < KNB; ++k) ws += iw[n * KNB + k];
    const bool  zs  = (ws == 0.f);
    const float inv = zs ? (1.f / KNB) : (1.f / ws);
    float4 p = make_float4(0.f, 0.f, 0.f, 0.f);
    #pragma unroll 1
    for (int kb = 0; kb < KNB; kb += 8) {
        int idx[8]; float w[8];
        #pragma unroll
        for (int k = 0; k < 8; ++k) { idx[k] = nbr[n*KNB+kb+k]; w[k] = iw[n*KNB+kb+k]; }
        #pragma unroll
        for (int k = 0; k < 8; ++k) {
            const float  wk = zs ? inv : (w[k] * inv);
            const float4 f  = *(const float4*)(feat + (size_t)idx[k] * D + lane * 4);
            p.x += wk*f.x; p.y += wk*f.y; p.z += wk*f.z; p.w += wk*f.w;
        }
    }
    ushort4 o;
    o.x = f2bf(p.x); o.y = f2bf(p.y); o.z = f2bf(p.z); o.w = f2bf(p.w);
    *(ushort4*)(aggb + (size_t)n * 512 + lane * 4) = o;
}

// ---------------- K2: bf16 MFMA GEMM + LayerNorm --------------------------
// 4 blocks/CU x 4 waves; per-wave LDS transpose scratch, no barriers.
#define WSTR 272   // per-quad-row float stride: 272%32=16 -> 2-way alias = free
__global__ __launch_bounds__(256, 4) void gemm_ln(const unsigned short* __restrict__ aggb,
                                                  const unsigned short* __restrict__ wtp,
                                                  const float* __restrict__ bias,
                                                  const float* __restrict__ gamma,
                                                  const float* __restrict__ beta,
                                                  float* __restrict__ out) {
    __shared__ float fsh[4][4 * WSTR];              // 17408 B; one slab per wave

    const int t       = threadIdx.x;
    const int lane    = t & 63;
    const int wq      = t >> 6;
    const int quad    = lane >> 4;
    const int l15     = lane & 15;
    const int rowbase = blockIdx.x * 64 + wq * 16;

    const int arow = min(rowbase + l15, NN - 1);
    const unsigned short* aptr = aggb + (size_t)arow * 512 + quad * 8;
    const short8* wv = (const short8*)wtp;

    f32x4 acc[16];
    #pragma unroll
    for (int c = 0; c < 16; ++c) acc[c] = (f32x4){0.f, 0.f, 0.f, 0.f};

    #pragma unroll
    for (int kb = 0; kb < 8; ++kb) {
        const short8 a = *(const short8*)(aptr + kb * 32);
        #pragma unroll
        for (int c = 0; c < 16; ++c) {
            const short8 b = wv[(size_t)(c * 8 + kb) * 64 + lane];  // dense 1 KB, L2-hot
            acc[c] = __builtin_amdgcn_mfma_f32_16x16x32_bf16(a, b, acc[c], 0, 0, 0);
        }
    }

    // Epilogue: +bias, LN, per-wave transpose in LDS, gamma/beta after
    // transpose (col = lane*4 -> 2 hoisted float4s), coalesced stores.
    float bv[16];
    #pragma unroll
    for (int c = 0; c < 16; ++c) bv[c] = bias[c * 16 + l15];
    const float4 gv4 = *(const float4*)(gamma + lane * 4);
    const float4 bt4 = *(const float4*)(beta  + lane * 4);
    float* wsh = fsh[wq];

    #pragma unroll
    for (int j = 0; j < 4; ++j) {       // C/D: row = quad*4 + j, col = c*16 + l15
        float s = 0.f, sq = 0.f;
        #pragma unroll
        for (int c = 0; c < 16; ++c) {
            const float v = acc[c][j] + bv[c];
            s += v; sq += v * v;
        }
        #pragma unroll
        for (int off = 1; off < 16; off <<= 1) {   // reduce across l15 (same quad)
            s  += __shfl_xor(s,  off, 64);
            sq += __shfl_xor(sq, off, 64);
        }
        const float mean = s * (1.f / D);
        const float var  = sq * (1.f / D) - mean * mean;   // biased (torch LN)
        const float rstd = rsqrtf(var + 1e-5f);
        #pragma unroll
        for (int c = 0; c < 16; ++c)               // row quad*4+j -> slab slot quad
            wsh[quad * WSTR + c * 16 + l15] = (acc[c][j] + bv[c] - mean) * rstd;
        // same-wave LDS dependency: compiler inserts lgkmcnt wait, no barrier
        #pragma unroll
        for (int p = 0; p < 4; ++p) {              // rows {j, 4+j, 8+j, 12+j}
            const long  r  = rowbase + p * 4 + j;
            const float4 v = *(const float4*)(wsh + p * WSTR + lane * 4);
            float4 o;
            o.x = v.x * gv4.x + bt4.x; o.y = v.y * gv4.y + bt4.y;
            o.z = v.z * gv4.z + bt4.z; o.w = v.w * gv4.w + bt4.w;
            *(float4*)(out + r * D + lane * 4) = o;   // coalesced 1 KB/instr
        }
    }
}

extern "C" void kernel_launch(void* const* d_in, const int* in_sizes, int n_in,
                              void* d_out, int out_size, void* d_ws, size_t ws_size,
                              hipStream_t stream) {
    const float* feat = (const float*)d_in[0];
    const int*   nbr  = (const int*)d_in[1];
    const float* iw   = (const float*)d_in[2];
    const float* Wm   = (const float*)d_in[3];
    const float* b    = (const float*)d_in[4];
    const float* g    = (const float*)d_in[5];
    const float* be   = (const float*)d_in[6];
    float*       out  = (float*)d_out;

    unsigned short* wtp   = (unsigned short*)d_ws;                   // 128 KB
    unsigned short* featb = (unsigned short*)((char*)d_ws + 131072); // 25.6 MB
    unsigned short* aggb  = (unsigned short*)d_out;                  // bf16 rows @ 1 KB

    const size_t need = 131072 + (size_t)NN * D * 2;

    if (ws_size >= need) {
        convert_all<<<dim3(6282),    dim3(256), 0, stream>>>(feat, Wm, featb, wtp);
        pool_b     <<<dim3(NN / 4),  dim3(256), 0, stream>>>(featb, nbr, iw, aggb);
    } else {
        convert_all<<<dim3(32 + 6250), dim3(256), 0, stream>>>(feat, Wm, featb, wtp); // still writes wtp
        pool_f     <<<dim3(NN / 4),  dim3(256), 0, stream>>>(feat, nbr, iw, aggb);
    }
    gemm_ln<<<dim3((NN + 63) / 64), dim3(256), 0, stream>>>(aggb, wtp, b, g, be, out);
}

// Round 8
// 187.966 us; speedup vs baseline: 1.5120x; 1.1776x over previous
//
#include <hip/hip_runtime.h>

// ImportanceAggregator pipeline:
//   K0 convert_all : feat fp32 -> featb bf16  AND  W -> wtp bf16 (B-frag order)
//   K1 pool_b      : agg[n] = sum_k w~[n,k] * featb[nbr[n,k]]; one wave/node.
//                    At the L3->L2 fill floor (~175 MB @ ~3.1 TB/s, R2-R7).
//   K2 gemm_ln     : out = LN(agg @ W + b)*gamma + beta via MFMA 16x16x32.
//                    Per-wave LDS transpose slabs (17.4 KB/block, no barriers),
//                    NO min-waves bound: kernel needs ~150 VGPR; (256,4) in
//                    R5/R7 forced a 64-reg cap -> scratch spill (WRITE 104 MB,
//                    66 us). Natural allocation -> 12 waves/CU, no spill.
// Lessons pinned: no 64-thread blocks (R6: 8 wg/CU slot limit); no hoisted
// runtime-indexed arrays (R4: alloca->LDS); coalesced float4 epilogue beats
// segment stores (R3 vs R5); launch_bounds min-waves is a VGPR cap (R7).
// agg bf16 rows live in d_out at 1 KB stride; each gemm_ln block reads only its
// own 64 rows then overwrites exactly those rows -> no cross-block hazard.

#define NN   50000
#define KNB  16
#define D    256

typedef __attribute__((ext_vector_type(8))) short short8;   // 8 x bf16 (4 VGPRs)
typedef __attribute__((ext_vector_type(4))) float f32x4;

static __device__ __forceinline__ unsigned short f2bf(float x) {
    unsigned int u = __float_as_uint(x);
    return (unsigned short)((u + 0x7FFFu + ((u >> 16) & 1u)) >> 16);  // RNE
}
static __device__ __forceinline__ float bf2f(unsigned short h) {
    return __uint_as_float((unsigned int)h << 16);
}

// ---------------- K0: both conversions in one dispatch --------------------
// blocks [0,6250): feat fp32 -> bf16 (8 elem/thread).
// blocks [6250,6282): W -> bf16 packed so frag g=(c*8+kb)*64+lane holds
//   B[k = (lane>>4)*8 + kb*32 + j][n = c*16 + (lane&15)]  (R3-proven layout).
__global__ __launch_bounds__(256) void convert_all(const float* __restrict__ feat,
                                                   const float* __restrict__ Wm,
                                                   unsigned short* __restrict__ featb,
                                                   unsigned short* __restrict__ wtp) {
    if (blockIdx.x < 6250) {
        const size_t g = (size_t)blockIdx.x * 256 + threadIdx.x;
        const float4 a = *(const float4*)(feat + g * 8);
        const float4 b = *(const float4*)(feat + g * 8 + 4);
        short8 o;
        o[0] = (short)f2bf(a.x); o[1] = (short)f2bf(a.y);
        o[2] = (short)f2bf(a.z); o[3] = (short)f2bf(a.w);
        o[4] = (short)f2bf(b.x); o[5] = (short)f2bf(b.y);
        o[6] = (short)f2bf(b.z); o[7] = (short)f2bf(b.w);
        *(short8*)(featb + g * 8) = o;
    } else {
        const int g    = (blockIdx.x - 6250) * 256 + threadIdx.x;   // 0..8191
        const int lane = g & 63;
        const int kb   = (g >> 6) & 7;
        const int c    = g >> 9;
        const int n    = c * 16 + (lane & 15);
        const int k0   = kb * 32 + (lane >> 4) * 8;
        short8 v;
        #pragma unroll
        for (int j = 0; j < 8; ++j) v[j] = (short)f2bf(Wm[(size_t)(k0 + j) * D + n]);
        *(short8*)(wtp + (size_t)g * 8) = v;
    }
}

// ---------------- K1: weighted neighbor pooling (bf16 gathers) ------------
// R3-proven form. NOTE: idx[]/w[] must stay inside the loop with constant
// indices only -> registers (hoisting triggers LDS promotion, see R4).
__global__ __launch_bounds__(256, 8) void pool_b(const unsigned short* __restrict__ featb,
                                                 const int*   __restrict__ nbr,
                                                 const float* __restrict__ iw,
                                                 unsigned short* __restrict__ aggb) {
    const int  t    = threadIdx.x;
    const int  lane = t & 63;
    const int  wq   = t >> 6;
    const long n    = (long)blockIdx.x * 4 + wq;   // one wave per node

    float ws = 0.f;
    #pragma unroll
    for (int k = 0; k < KNB; ++k) ws += iw[n * KNB + k];
    const bool  zs  = (ws == 0.f);
    const float inv = zs ? (1.f / KNB) : (1.f / ws);

    float4 p = make_float4(0.f, 0.f, 0.f, 0.f);
    #pragma unroll 1
    for (int kb = 0; kb < KNB; kb += 8) {          // 8 gathers in flight per batch
        int   idx[8];
        float w[8];
        #pragma unroll
        for (int k = 0; k < 8; ++k) {
            idx[k] = nbr[n * KNB + kb + k];
            w[k]   = iw [n * KNB + kb + k];
        }
        #pragma unroll
        for (int k = 0; k < 8; ++k) {
            const float   wk = zs ? inv : (w[k] * inv);
            const ushort4 u  = *(const ushort4*)(featb + (size_t)idx[k] * D + lane * 4);
            p.x += wk * bf2f(u.x); p.y += wk * bf2f(u.y);
            p.z += wk * bf2f(u.z); p.w += wk * bf2f(u.w);
        }
    }
    ushort4 o;
    o.x = f2bf(p.x); o.y = f2bf(p.y); o.z = f2bf(p.z); o.w = f2bf(p.w);
    *(ushort4*)(aggb + (size_t)n * 512 + lane * 4) = o;   // row n @ 1 KB stride
}

// Fallback (ws too small for featb): fp32 gathers, one node per wave.
__global__ __launch_bounds__(256, 8) void pool_f(const float* __restrict__ feat,
                                                 const int*   __restrict__ nbr,
                                                 const float* __restrict__ iw,
                                                 unsigned short* __restrict__ aggb) {
    const int  t    = threadIdx.x;
    const int  lane = t & 63;
    const int  wq   = t >> 6;
    const long n    = (long)blockIdx.x * 4 + wq;
    float ws = 0.f;
    #pragma unroll
    for (int k = 0; k < KNB; ++k) ws += iw[n * KNB + k];
    const bool  zs  = (ws == 0.f);
    const float inv = zs ? (1.f / KNB) : (1.f / ws);
    float4 p = make_float4(0.f, 0.f, 0.f, 0.f);
    #pragma unroll 1
    for (int kb = 0; kb < KNB; kb += 8) {
        int idx[8]; float w[8];
        #pragma unroll
        for (int k = 0; k < 8; ++k) { idx[k] = nbr[n*KNB+kb+k]; w[k] = iw[n*KNB+kb+k]; }
        #pragma unroll
        for (int k = 0; k < 8; ++k) {
            const float  wk = zs ? inv : (w[k] * inv);
            const float4 f  = *(const float4*)(feat + (size_t)idx[k] * D + lane * 4);
            p.x += wk*f.x; p.y += wk*f.y; p.z += wk*f.z; p.w += wk*f.w;
        }
    }
    ushort4 o;
    o.x = f2bf(p.x); o.y = f2bf(p.y); o.z = f2bf(p.z); o.w = f2bf(p.w);
    *(ushort4*)(aggb + (size_t)n * 512 + lane * 4) = o;
}

// ---------------- K2: bf16 MFMA GEMM + LayerNorm --------------------------
// Per-wave LDS transpose scratch, no barriers. NO min-waves bound: natural
// VGPR allocation (~150) -> 3 waves/EU, no spill (R7: (256,4) capped regs at
// 64 -> 52 MB scratch spill traffic, 66 us).
#define WSTR 272   // per-quad-row float stride: 272%32=16 -> 2-way alias = free
__global__ __launch_bounds__(256) void gemm_ln(const unsigned short* __restrict__ aggb,
                                               const unsigned short* __restrict__ wtp,
                                               const float* __restrict__ bias,
                                               const float* __restrict__ gamma,
                                               const float* __restrict__ beta,
                                               float* __restrict__ out) {
    __shared__ float fsh[4][4 * WSTR];              // 17408 B; one slab per wave

    const int t       = threadIdx.x;
    const int lane    = t & 63;
    const int wq      = t >> 6;
    const int quad    = lane >> 4;
    const int l15     = lane & 15;
    const int rowbase = blockIdx.x * 64 + wq * 16;

    const int arow = min(rowbase + l15, NN - 1);
    const unsigned short* aptr = aggb + (size_t)arow * 512 + quad * 8;
    const short8* wv = (const short8*)wtp;

    f32x4 acc[16];
    #pragma unroll
    for (int c = 0; c < 16; ++c) acc[c] = (f32x4){0.f, 0.f, 0.f, 0.f};

    #pragma unroll
    for (int kb = 0; kb < 8; ++kb) {
        const short8 a = *(const short8*)(aptr + kb * 32);
        #pragma unroll
        for (int c = 0; c < 16; ++c) {
            const short8 b = wv[(size_t)(c * 8 + kb) * 64 + lane];  // dense 1 KB, L2-hot
            acc[c] = __builtin_amdgcn_mfma_f32_16x16x32_bf16(a, b, acc[c], 0, 0, 0);
        }
    }

    // Epilogue: +bias, LN, per-wave transpose in LDS, gamma/beta after
    // transpose (col = lane*4 -> 2 hoisted float4s), coalesced stores.
    float bv[16];
    #pragma unroll
    for (int c = 0; c < 16; ++c) bv[c] = bias[c * 16 + l15];
    const float4 gv4 = *(const float4*)(gamma + lane * 4);
    const float4 bt4 = *(const float4*)(beta  + lane * 4);
    float* wsh = fsh[wq];

    #pragma unroll
    for (int j = 0; j < 4; ++j) {       // C/D: row = quad*4 + j, col = c*16 + l15
        float s = 0.f, sq = 0.f;
        #pragma unroll
        for (int c = 0; c < 16; ++c) {
            const float v = acc[c][j] + bv[c];
            s += v; sq += v * v;
        }
        #pragma unroll
        for (int off = 1; off < 16; off <<= 1) {   // reduce across l15 (same quad)
            s  += __shfl_xor(s,  off, 64);
            sq += __shfl_xor(sq, off, 64);
        }
        const float mean = s * (1.f / D);
        const float var  = sq * (1.f / D) - mean * mean;   // biased (torch LN)
        const float rstd = rsqrtf(var + 1e-5f);
        #pragma unroll
        for (int c = 0; c < 16; ++c)               // row quad*4+j -> slab slot quad
            wsh[quad * WSTR + c * 16 + l15] = (acc[c][j] + bv[c] - mean) * rstd;
        // same-wave LDS dependency: compiler inserts lgkmcnt wait, no barrier
        #pragma unroll
        for (int p = 0; p < 4; ++p) {              // rows {j, 4+j, 8+j, 12+j}
            const long  r  = rowbase + p * 4 + j;
            const float4 v = *(const float4*)(wsh + p * WSTR + lane * 4);
            float4 o;
            o.x = v.x * gv4.x + bt4.x; o.y = v.y * gv4.y + bt4.y;
            o.z = v.z * gv4.z + bt4.z; o.w = v.w * gv4.w + bt4.w;
            *(float4*)(out + r * D + lane * 4) = o;   // coalesced 1 KB/instr
        }
    }
}

extern "C" void kernel_launch(void* const* d_in, const int* in_sizes, int n_in,
                              void* d_out, int out_size, void* d_ws, size_t ws_size,
                              hipStream_t stream) {
    const float* feat = (const float*)d_in[0];
    const int*   nbr  = (const int*)d_in[1];
    const float* iw   = (const float*)d_in[2];
    const float* Wm   = (const float*)d_in[3];
    const float* b    = (const float*)d_in[4];
    const float* g    = (const float*)d_in[5];
    const float* be   = (const float*)d_in[6];
    float*       out  = (float*)d_out;

    unsigned short* wtp   = (unsigned short*)d_ws;                   // 128 KB
    unsigned short* featb = (unsigned short*)((char*)d_ws + 131072); // 25.6 MB
    unsigned short* aggb  = (unsigned short*)d_out;                  // bf16 rows @ 1 KB

    const size_t need = 131072 + (size_t)NN * D * 2;

    if (ws_size >= need) {
        convert_all<<<dim3(6282),    dim3(256), 0, stream>>>(feat, Wm, featb, wtp);
        pool_b     <<<dim3(NN / 4),  dim3(256), 0, stream>>>(featb, nbr, iw, aggb);
    } else {
        convert_all<<<dim3(32 + 6250), dim3(256), 0, stream>>>(feat, Wm, featb, wtp);
        pool_f     <<<dim3(NN / 4),  dim3(256), 0, stream>>>(feat, nbr, iw, aggb);
    }
    gemm_ln<<<dim3((NN + 63) / 64), dim3(256), 0, stream>>>(aggb, wtp, b, g, be, out);
}

// Round 9
// 186.747 us; speedup vs baseline: 1.5218x; 1.0065x over previous
//
#include <hip/hip_runtime.h>

// ImportanceAggregator pipeline:
//   K0 convert_all : feat fp32 -> featb bf16  AND  W -> wtp bf16, kb-major
//                    B-frag order (16 KB per 32-k chunk, contiguous).
//   K1 pool_b      : agg[n] = sum_k w~[n,k] * featb[nbr[n,k]]; one wave/node.
//                    At the per-XCD L2 fill floor (~175 MB @ ~3.6 TB/s, R2-R8).
//   K2 gemm_ln     : out = LN(agg @ W + b)*gamma + beta via MFMA 16x16x32.
//                    NEW: B staged through LDS (2 x 16 KB double buffer, one
//                    barrier/chunk, hand-pipelined reg staging) -> 4 waves
//                    share one L2 B-stream (400->100 MB) and read B as
//                    conflict-free ds_read_b128 instead of 128 latency-exposed
//                    L2 loads per wave. Epilogue: per-wave LDS slabs (R8).
// Lessons pinned: no 64-thread blocks (R6); no hoisted runtime-indexed arrays
// (R4 alloca->LDS); float4 epilogue beats segment stores (R3 vs R5);
// launch_bounds min-waves is a VGPR cap -> spill (R7); natural alloc (R8).
// agg bf16 rows live in d_out at 1 KB stride; each gemm_ln block reads only
// its own 64 rows then overwrites exactly those rows -> no cross-block hazard.

#define NN   50000
#define KNB  16
#define D    256
#define WSTR 272   // epilogue slab stride (floats): 272%32=16 -> 2-way alias = free

typedef __attribute__((ext_vector_type(8))) short short8;   // 8 x bf16 (4 VGPRs)
typedef __attribute__((ext_vector_type(4))) float f32x4;

static __device__ __forceinline__ unsigned short f2bf(float x) {
    unsigned int u = __float_as_uint(x);
    return (unsigned short)((u + 0x7FFFu + ((u >> 16) & 1u)) >> 16);  // RNE
}
static __device__ __forceinline__ float bf2f(unsigned short h) {
    return __uint_as_float((unsigned int)h << 16);
}

// ---------------- K0: both conversions in one dispatch --------------------
// blocks [0,nfb): feat fp32 -> bf16 (8 elem/thread).
// blocks [nfb,nfb+32): W -> bf16 packed kb-major: frag g=(kb*16+c)*64+lane
//   holds B[k = kb*32 + (lane>>4)*8 + j][n = c*16 + (lane&15)], so chunk kb
//   is one contiguous 16 KB block (LDS-stageable with linear copies).
__global__ __launch_bounds__(256) void convert_all(const float* __restrict__ feat,
                                                   const float* __restrict__ Wm,
                                                   unsigned short* __restrict__ featb,
                                                   unsigned short* __restrict__ wtp,
                                                   int nfb) {
    if ((int)blockIdx.x < nfb) {
        const size_t g = (size_t)blockIdx.x * 256 + threadIdx.x;
        const float4 a = *(const float4*)(feat + g * 8);
        const float4 b = *(const float4*)(feat + g * 8 + 4);
        short8 o;
        o[0] = (short)f2bf(a.x); o[1] = (short)f2bf(a.y);
        o[2] = (short)f2bf(a.z); o[3] = (short)f2bf(a.w);
        o[4] = (short)f2bf(b.x); o[5] = (short)f2bf(b.y);
        o[6] = (short)f2bf(b.z); o[7] = (short)f2bf(b.w);
        *(short8*)(featb + g * 8) = o;
    } else {
        const int g    = (blockIdx.x - nfb) * 256 + threadIdx.x;    // 0..8191
        const int lane = g & 63;
        const int c    = (g >> 6) & 15;
        const int kb   = g >> 10;
        const int n    = c * 16 + (lane & 15);
        const int k0   = kb * 32 + (lane >> 4) * 8;
        short8 v;
        #pragma unroll
        for (int j = 0; j < 8; ++j) v[j] = (short)f2bf(Wm[(size_t)(k0 + j) * D + n]);
        *(short8*)(wtp + (size_t)g * 8) = v;
    }
}

// ---------------- K1: weighted neighbor pooling (bf16 gathers) ------------
// R3-proven form. NOTE: idx[]/w[] must stay inside the loop with constant
// indices only -> registers (hoisting triggers LDS promotion, see R4).
__global__ __launch_bounds__(256, 8) void pool_b(const unsigned short* __restrict__ featb,
                                                 const int*   __restrict__ nbr,
                                                 const float* __restrict__ iw,
                                                 unsigned short* __restrict__ aggb) {
    const int  t    = threadIdx.x;
    const int  lane = t & 63;
    const int  wq   = t >> 6;
    const long n    = (long)blockIdx.x * 4 + wq;   // one wave per node

    float ws = 0.f;
    #pragma unroll
    for (int k = 0; k < KNB; ++k) ws += iw[n * KNB + k];
    const bool  zs  = (ws == 0.f);
    const float inv = zs ? (1.f / KNB) : (1.f / ws);

    float4 p = make_float4(0.f, 0.f, 0.f, 0.f);
    #pragma unroll 1
    for (int kb = 0; kb < KNB; kb += 8) {          // 8 gathers in flight per batch
        int   idx[8];
        float w[8];
        #pragma unroll
        for (int k = 0; k < 8; ++k) {
            idx[k] = nbr[n * KNB + kb + k];
            w[k]   = iw [n * KNB + kb + k];
        }
        #pragma unroll
        for (int k = 0; k < 8; ++k) {
            const float   wk = zs ? inv : (w[k] * inv);
            const ushort4 u  = *(const ushort4*)(featb + (size_t)idx[k] * D + lane * 4);
            p.x += wk * bf2f(u.x); p.y += wk * bf2f(u.y);
            p.z += wk * bf2f(u.z); p.w += wk * bf2f(u.w);
        }
    }
    ushort4 o;
    o.x = f2bf(p.x); o.y = f2bf(p.y); o.z = f2bf(p.z); o.w = f2bf(p.w);
    *(ushort4*)(aggb + (size_t)n * 512 + lane * 4) = o;   // row n @ 1 KB stride
}

// Fallback (ws too small for featb): fp32 gathers, one wave per node.
__global__ __launch_bounds__(256, 8) void pool_f(const float* __restrict__ feat,
                                                 const int*   __restrict__ nbr,
                                                 const float* __restrict__ iw,
                                                 unsigned short* __restrict__ aggb) {
    const int  t    = threadIdx.x;
    const int  lane = t & 63;
    const int  wq   = t >> 6;
    const long n    = (long)blockIdx.x * 4 + wq;
    float ws = 0.f;
    #pragma unroll
    for (int k = 0; k < KNB; ++k) ws += iw[n * KNB + k];
    const bool  zs  = (ws == 0.f);
    const float inv = zs ? (1.f / KNB) : (1.f / ws);
    float4 p = make_float4(0.f, 0.f, 0.f, 0.f);
    #pragma unroll 1
    for (int kb = 0; kb < KNB; kb += 8) {
        int idx[8]; float w[8];
        #pragma unroll
        for (int k = 0; k < 8; ++k) { idx[k] = nbr[n*KNB+kb+k]; w[k] = iw[n*KNB+kb+k]; }
        #pragma unroll
        for (int k = 0; k < 8; ++k) {
            const float  wk = zs ? inv : (w[k] * inv);
            const float4 f  = *(const float4*)(feat + (size_t)idx[k] * D + lane * 4);
            p.x += wk*f.x; p.y += wk*f.y; p.z += wk*f.z; p.w += wk*f.w;
        }
    }
    ushort4 o;
    o.x = f2bf(p.x); o.y = f2bf(p.y); o.z = f2bf(p.z); o.w = f2bf(p.w);
    *(ushort4*)(aggb + (size_t)n * 512 + lane * 4) = o;
}

// ---------------- K2: bf16 MFMA GEMM + LayerNorm, LDS-staged B ------------
// Block = 4 waves x 16 rows. B chunk (32 k x 256 n = 16 KB) double-buffered in
// LDS, shared by all 4 waves; one barrier per chunk. Staging hand-pipelined:
// global loads -> regs BEFORE the MFMA burst, ds_writes after, then barrier.
__global__ __launch_bounds__(256) void gemm_ln(const unsigned short* __restrict__ aggb,
                                               const unsigned short* __restrict__ wtp,
                                               const float* __restrict__ bias,
                                               const float* __restrict__ gamma,
                                               const float* __restrict__ beta,
                                               float* __restrict__ out) {
    __shared__ short sB[2][8192];                   // 2 x 16 KB B chunks
    __shared__ float fsh[4][4 * WSTR];              // 17.4 KB epilogue slabs

    const int t       = threadIdx.x;
    const int lane    = t & 63;
    const int wq      = t >> 6;
    const int quad    = lane >> 4;
    const int l15     = lane & 15;
    const int rowbase = blockIdx.x * 64 + wq * 16;

    const int arow = min(rowbase + l15, NN - 1);
    const unsigned short* aptr = aggb + (size_t)arow * 512 + quad * 8;
    const short8* wv = (const short8*)wtp;          // frag u of chunk kb: wv[kb*1024+u]

    // Prefetch all 8 A-frags (independent 16 B loads, issued up front).
    short8 aF[8];
    #pragma unroll
    for (int kb = 0; kb < 8; ++kb) aF[kb] = *(const short8*)(aptr + kb * 32);

    // Stage chunk 0.
    #pragma unroll
    for (int i = 0; i < 4; ++i)
        *(short8*)&sB[0][(size_t)(i * 256 + t) * 8] = wv[i * 256 + t];
    __syncthreads();

    f32x4 acc[16];
    #pragma unroll
    for (int c = 0; c < 16; ++c) acc[c] = (f32x4){0.f, 0.f, 0.f, 0.f};

    #pragma unroll
    for (int kb = 0; kb < 8; ++kb) {
        const int buf = kb & 1;
        short8 stg[4];
        if (kb < 7) {                               // issue next-chunk loads now
            #pragma unroll
            for (int i = 0; i < 4; ++i)
                stg[i] = wv[(size_t)(kb + 1) * 1024 + i * 256 + t];
        }
        #pragma unroll
        for (int c = 0; c < 16; ++c) {              // conflict-free ds_read_b128
            const short8 b = *(const short8*)&sB[buf][(size_t)(c * 64 + lane) * 8];
            acc[c] = __builtin_amdgcn_mfma_f32_16x16x32_bf16(aF[kb], b, acc[c], 0, 0, 0);
        }
        if (kb < 7) {                               // park next chunk in other buffer
            #pragma unroll
            for (int i = 0; i < 4; ++i)
                *(short8*)&sB[buf ^ 1][(size_t)(i * 256 + t) * 8] = stg[i];
        }
        __syncthreads();                            // one barrier per chunk
    }

    // Epilogue: +bias, LN, per-wave transpose slab, gamma/beta after
    // transpose (col = lane*4 -> 2 hoisted float4s), coalesced float4 stores.
    float bv[16];
    #pragma unroll
    for (int c = 0; c < 16; ++c) bv[c] = bias[c * 16 + l15];
    const float4 gv4 = *(const float4*)(gamma + lane * 4);
    const float4 bt4 = *(const float4*)(beta  + lane * 4);
    float* wsh = fsh[wq];

    #pragma unroll
    for (int j = 0; j < 4; ++j) {       // C/D: row = quad*4 + j, col = c*16 + l15
        float s = 0.f, sq = 0.f;
        #pragma unroll
        for (int c = 0; c < 16; ++c) {
            const float v = acc[c][j] + bv[c];
            s += v; sq += v * v;
        }
        #pragma unroll
        for (int off = 1; off < 16; off <<= 1) {   // reduce across l15 (same quad)
            s  += __shfl_xor(s,  off, 64);
            sq += __shfl_xor(sq, off, 64);
        }
        const float mean = s * (1.f / D);
        const float var  = sq * (1.f / D) - mean * mean;   // biased (torch LN)
        const float rstd = rsqrtf(var + 1e-5f);
        #pragma unroll
        for (int c = 0; c < 16; ++c)               // row quad*4+j -> slab slot quad
            wsh[quad * WSTR + c * 16 + l15] = (acc[c][j] + bv[c] - mean) * rstd;
        // same-wave LDS dependency: compiler inserts lgkmcnt wait, no barrier
        #pragma unroll
        for (int p = 0; p < 4; ++p) {              // rows {j, 4+j, 8+j, 12+j}
            const long  r  = rowbase + p * 4 + j;
            if (r < NN) {
                const float4 v = *(const float4*)(wsh + p * WSTR + lane * 4);
                float4 o;
                o.x = v.x * gv4.x + bt4.x; o.y = v.y * gv4.y + bt4.y;
                o.z = v.z * gv4.z + bt4.z; o.w = v.w * gv4.w + bt4.w;
                *(float4*)(out + r * D + lane * 4) = o;   // coalesced 1 KB/instr
            }
        }
    }
}

extern "C" void kernel_launch(void* const* d_in, const int* in_sizes, int n_in,
                              void* d_out, int out_size, void* d_ws, size_t ws_size,
                              hipStream_t stream) {
    const float* feat = (const float*)d_in[0];
    const int*   nbr  = (const int*)d_in[1];
    const float* iw   = (const float*)d_in[2];
    const float* Wm   = (const float*)d_in[3];
    const float* b    = (const float*)d_in[4];
    const float* g    = (const float*)d_in[5];
    const float* be   = (const float*)d_in[6];
    float*       out  = (float*)d_out;

    unsigned short* wtp   = (unsigned short*)d_ws;                   // 128 KB
    unsigned short* featb = (unsigned short*)((char*)d_ws + 131072); // 25.6 MB
    unsigned short* aggb  = (unsigned short*)d_out;                  // bf16 rows @ 1 KB

    const size_t need = 131072 + (size_t)NN * D * 2;

    if (ws_size >= need) {
        convert_all<<<dim3(6282),   dim3(256), 0, stream>>>(feat, Wm, featb, wtp, 6250);
        pool_b     <<<dim3(NN / 4), dim3(256), 0, stream>>>(featb, nbr, iw, aggb);
    } else {
        convert_all<<<dim3(32),     dim3(256), 0, stream>>>(feat, Wm, featb, wtp, 0);
        pool_f     <<<dim3(NN / 4), dim3(256), 0, stream>>>(feat, nbr, iw, aggb);
    }
    gemm_ln<<<dim3((NN + 63) / 64), dim3(256), 0, stream>>>(aggb, wtp, b, g, be, out);
}